// Round 1
// baseline (2119.132 us; speedup 1.0000x reference)
//
#include <hip/hip_runtime.h>
#include <hip/hip_bf16.h>
#include <math.h>

// Problem constants (match reference)
#define N_TOKENS 16
#define TOK_DIM 64
#define NODE_DIM 64
#define HID 128
#define FC 128
#define NUM_GRAPHS 1024

// ---------------- K1: embedding gather + mean over tokens + 64x64 projection ----------------
// one block (64 threads) per node
__global__ void embed_project_kernel(const int* __restrict__ tok,
                                     const float* __restrict__ emb,
                                     const float* __restrict__ Wp,
                                     const float* __restrict__ bp,
                                     float* __restrict__ node,
                                     int N) {
    int i = blockIdx.x;
    if (i >= N) return;
    int j = threadIdx.x;  // 0..63
    __shared__ float mean[TOK_DIM];
    float s = 0.f;
#pragma unroll
    for (int t = 0; t < N_TOKENS; t++) {
        int v = tok[i * N_TOKENS + t];
        s += emb[v * TOK_DIM + j];
    }
    mean[j] = s * (1.0f / (float)N_TOKENS);
    __syncthreads();
    float acc = bp[j];
#pragma unroll
    for (int k = 0; k < TOK_DIM; k++) acc += mean[k] * Wp[k * NODE_DIM + j];
    node[i * NODE_DIM + j] = acc;
}

// ---------------- K2: degree (self-loop => start at 1) ----------------
__global__ void deg_init_kernel(float* __restrict__ deg, int N) {
    int i = blockIdx.x * blockDim.x + threadIdx.x;
    if (i < N) deg[i] = 1.0f;  // self loop
}

__global__ void deg_count_kernel(const int* __restrict__ dst, float* __restrict__ deg, int E) {
    int e = blockIdx.x * blockDim.x + threadIdx.x;
    if (e < E) atomicAdd(&deg[dst[e]], 1.0f);
}

__global__ void deg_rsqrt_kernel(float* __restrict__ deg, int N) {
    int i = blockIdx.x * blockDim.x + threadIdx.x;
    if (i < N) deg[i] = rsqrtf(deg[i]);  // deg >= 1 always (self loop)
}

// ---------------- K3: dense linears ----------------
// x[N,64] @ W[64,128] -> h[N,128]; 256 threads = 2 nodes/block
__global__ void linear_64_128_kernel(const float* __restrict__ x,
                                     const float* __restrict__ W,
                                     float* __restrict__ h, int N) {
    int t = threadIdx.x;
    int nodeBase = blockIdx.x * 2;
    __shared__ float sx[2][64];
    {
        int li = nodeBase + (t >> 6);
        if (t < 128 && li < N) sx[t >> 6][t & 63] = x[li * 64 + (t & 63)];
    }
    __syncthreads();
    int node = nodeBase + (t >> 7);
    int j = t & 127;
    if (node < N) {
        const float* xr = sx[t >> 7];
        float acc = 0.f;
#pragma unroll
        for (int k = 0; k < 64; k++) acc += xr[k] * W[k * 128 + j];
        h[node * 128 + j] = acc;
    }
}

// x[N,128] @ W[128,128] -> h[N,128]; 256 threads = 2 nodes/block
__global__ void linear_128_128_kernel(const float* __restrict__ x,
                                      const float* __restrict__ W,
                                      float* __restrict__ h, int N) {
    int t = threadIdx.x;
    int nodeBase = blockIdx.x * 2;
    __shared__ float sx[2][128];
    {
        int li = nodeBase + (t >> 7);
        if (li < N) sx[t >> 7][t & 127] = x[li * 128 + (t & 127)];
    }
    __syncthreads();
    int node = nodeBase + (t >> 7);
    int j = t & 127;
    if (node < N) {
        const float* xr = sx[t >> 7];
        float acc = 0.f;
#pragma unroll
        for (int k = 0; k < 128; k++) acc += xr[k] * W[k * 128 + j];
        h[node * 128 + j] = acc;
    }
}

// ---------------- K4: GCN aggregation ----------------
// init output with self-loop term + bias: out[i,j] = h[i,j]*dis[i]^2 + b[j]
__global__ void gcn_init_kernel(const float* __restrict__ h,
                                const float* __restrict__ dis,
                                const float* __restrict__ b,
                                float* __restrict__ out, int N) {
    int idx = blockIdx.x * blockDim.x + threadIdx.x;
    if (idx < N * 128) {
        int i = idx >> 7;
        int j = idx & 127;
        float d = dis[i];
        out[idx] = h[idx] * d * d + b[j];
    }
}

// scatter-add edges: out[dst] += h[src] * dis[src]*dis[dst]; 256 threads = 2 edges/block
__global__ void gcn_scatter_kernel(const float* __restrict__ h,
                                   const int* __restrict__ src,
                                   const int* __restrict__ dst,
                                   const float* __restrict__ dis,
                                   float* __restrict__ out, int E) {
    int t = threadIdx.x;
    int e = blockIdx.x * 2 + (t >> 7);
    int j = t & 127;
    if (e < E) {
        int s = src[e];
        int d = dst[e];
        float nrm = dis[s] * dis[d];
        atomicAdd(&out[d * 128 + j], h[s * 128 + j] * nrm);
    }
}

__global__ void relu_kernel(float* __restrict__ x, int n) {
    int i = blockIdx.x * blockDim.x + threadIdx.x;
    if (i < n) x[i] = fmaxf(x[i], 0.f);
}

// ---------------- K5: global mean pool (atomic accumulate) ----------------
__global__ void pool_kernel(const float* __restrict__ x,
                            const int* __restrict__ batch,
                            float* __restrict__ g,
                            float* __restrict__ cnt, int N) {
    int t = threadIdx.x;
    int i = blockIdx.x * 2 + (t >> 7);
    int j = t & 127;
    if (i < N) {
        int b = batch[i];
        atomicAdd(&g[b * 128 + j], x[i * 128 + j]);
        if (j == 0) atomicAdd(&cnt[b], 1.0f);
    }
}

// ---------------- K6: head: mean, FC+ReLU, out proj, sigmoid ----------------
// one block (128 threads) per graph
__global__ void head_kernel(const float* __restrict__ g,
                            const float* __restrict__ cnt,
                            const float* __restrict__ Wfc,
                            const float* __restrict__ bfc,
                            const float* __restrict__ Wout,
                            const float* __restrict__ bout,
                            float* __restrict__ out) {
    int gr = blockIdx.x;
    int j = threadIdx.x;  // 0..127
    __shared__ float sg[128];
    __shared__ float sred[128];
    float c = fmaxf(cnt[gr], 1.0f);
    sg[j] = g[gr * 128 + j] / c;
    __syncthreads();
    float acc = bfc[j];
#pragma unroll
    for (int k = 0; k < 128; k++) acc += sg[k] * Wfc[k * 128 + j];
    float f = fmaxf(acc, 0.f);
    sred[j] = f * Wout[j];
    __syncthreads();
    if (j < 64) sred[j] += sred[j + 64];
    __syncthreads();
    if (j < 64) {
        float v = sred[j];
#pragma unroll
        for (int off = 32; off > 0; off >>= 1) v += __shfl_down(v, off);
        if (j == 0) {
            float logit = v + bout[0];
            out[gr] = 1.0f / (1.0f + expf(-logit));       // sigmoid
            out[NUM_GRAPHS + gr] = logit;                 // logits
        }
    }
}

extern "C" void kernel_launch(void* const* d_in, const int* in_sizes, int n_in,
                              void* d_out, int out_size, void* d_ws, size_t ws_size,
                              hipStream_t stream) {
    const int* tok   = (const int*)d_in[0];      // [N,16]
    const int* eidx  = (const int*)d_in[1];      // [2,E]
    const int* batch = (const int*)d_in[2];      // [N]
    const float* emb = (const float*)d_in[3];
    const float* Wp  = (const float*)d_in[4];
    const float* bp  = (const float*)d_in[5];
    const float* W1  = (const float*)d_in[6];
    const float* b1  = (const float*)d_in[7];
    const float* W2  = (const float*)d_in[8];
    const float* b2  = (const float*)d_in[9];
    const float* Wfc = (const float*)d_in[10];
    const float* bfc = (const float*)d_in[11];
    const float* Wout= (const float*)d_in[12];
    const float* bout= (const float*)d_in[13];
    float* out = (float*)d_out;

    const int N = in_sizes[2];
    const int E = in_sizes[1] / 2;
    const int* src = eidx;
    const int* dst = eidx + E;

    // workspace layout (floats)
    float* ws = (float*)d_ws;
    float* node = ws;                       // N*64
    float* dis  = node + (size_t)N * 64;    // N
    float* hbuf = dis + N;                  // N*128
    float* xbuf = hbuf + (size_t)N * 128;   // N*128
    float* g    = xbuf + (size_t)N * 128;   // 1024*128
    float* cnt  = g + NUM_GRAPHS * 128;     // 1024

    // K1: embed + mean + project
    embed_project_kernel<<<N, 64, 0, stream>>>(tok, emb, Wp, bp, node, N);

    // K2: degrees -> dis
    deg_init_kernel<<<(N + 255) / 256, 256, 0, stream>>>(dis, N);
    deg_count_kernel<<<(E + 255) / 256, 256, 0, stream>>>(dst, dis, E);
    deg_rsqrt_kernel<<<(N + 255) / 256, 256, 0, stream>>>(dis, N);

    // ----- GCN layer 1: node[N,64] -> x1[N,128] -----
    linear_64_128_kernel<<<(N + 1) / 2, 256, 0, stream>>>(node, W1, hbuf, N);
    gcn_init_kernel<<<(N * 128 + 255) / 256, 256, 0, stream>>>(hbuf, dis, b1, xbuf, N);
    gcn_scatter_kernel<<<(E + 1) / 2, 256, 0, stream>>>(hbuf, src, dst, dis, xbuf, E);
    relu_kernel<<<(N * 128 + 255) / 256, 256, 0, stream>>>(xbuf, N * 128);

    // ----- GCN layer 2: x1[N,128] -> x2[N,128] (reuse buffers) -----
    linear_128_128_kernel<<<(N + 1) / 2, 256, 0, stream>>>(xbuf, W2, hbuf, N);
    gcn_init_kernel<<<(N * 128 + 255) / 256, 256, 0, stream>>>(hbuf, dis, b2, xbuf, N);
    gcn_scatter_kernel<<<(E + 1) / 2, 256, 0, stream>>>(hbuf, src, dst, dis, xbuf, E);
    relu_kernel<<<(N * 128 + 255) / 256, 256, 0, stream>>>(xbuf, N * 128);

    // ----- global mean pool -----
    hipMemsetAsync(g, 0, (NUM_GRAPHS * 128 + NUM_GRAPHS) * sizeof(float), stream);
    pool_kernel<<<(N + 1) / 2, 256, 0, stream>>>(xbuf, batch, g, cnt, N);

    // ----- head -----
    head_kernel<<<NUM_GRAPHS, 128, 0, stream>>>(g, cnt, Wfc, bfc, Wout, bout, out);
}

// Round 2
// 869.266 us; speedup vs baseline: 2.4378x; 2.4378x over previous
//
#include <hip/hip_runtime.h>
#include <hip/hip_bf16.h>
#include <math.h>

#define N_TOKENS 16
#define TOK_DIM 64
#define NODE_DIM 64
#define HID 128
#define FC 128
#define NUM_GRAPHS 1024
#define SCAN_B 256

// ---------------- K1: embedding gather + mean over tokens + 64x64 projection ----------------
__global__ void embed_project_kernel(const int* __restrict__ tok,
                                     const float* __restrict__ emb,
                                     const float* __restrict__ Wp,
                                     const float* __restrict__ bp,
                                     float* __restrict__ node,
                                     int N) {
    int i = blockIdx.x;
    if (i >= N) return;
    int j = threadIdx.x;  // 0..63
    __shared__ float mean[TOK_DIM];
    float s = 0.f;
#pragma unroll
    for (int t = 0; t < N_TOKENS; t++) {
        int v = tok[i * N_TOKENS + t];
        s += emb[v * TOK_DIM + j];
    }
    mean[j] = s * (1.0f / (float)N_TOKENS);
    __syncthreads();
    float acc = bp[j];
#pragma unroll
    for (int k = 0; k < TOK_DIM; k++) acc += mean[k] * Wp[k * NODE_DIM + j];
    node[i * NODE_DIM + j] = acc;
}

// ---------------- degree histogram (int) ----------------
__global__ void hist_kernel(const int* __restrict__ dst, int* __restrict__ hist, int E) {
    int e = blockIdx.x * blockDim.x + threadIdx.x;
    if (e < E) atomicAdd(&hist[dst[e]], 1);
}

__global__ void dis_kernel(const int* __restrict__ hist, float* __restrict__ dis, int N) {
    int i = blockIdx.x * blockDim.x + threadIdx.x;
    if (i < N) dis[i] = rsqrtf(1.0f + (float)hist[i]);  // +1 self loop
}

// ---------------- exclusive scan (3 kernels) ----------------
__global__ void scan_local_kernel(const int* __restrict__ hist, int* __restrict__ row_start,
                                  int* __restrict__ bsums, int N) {
    __shared__ int s[SCAN_B];
    int tid = threadIdx.x;
    int i = blockIdx.x * SCAN_B + tid;
    int v = (i < N) ? hist[i] : 0;
    s[tid] = v;
    __syncthreads();
    for (int off = 1; off < SCAN_B; off <<= 1) {
        int add = (tid >= off) ? s[tid - off] : 0;
        __syncthreads();
        s[tid] += add;
        __syncthreads();
    }
    if (i < N) row_start[i] = s[tid] - v;  // exclusive
    if (tid == SCAN_B - 1) bsums[blockIdx.x] = s[SCAN_B - 1];
}

// single block, 512 threads; nb <= 512
__global__ void scan_bsums_kernel(int* __restrict__ bsums, int nb) {
    __shared__ int s[512];
    int tid = threadIdx.x;
    int v = (tid < nb) ? bsums[tid] : 0;
    s[tid] = v;
    __syncthreads();
    for (int off = 1; off < 512; off <<= 1) {
        int add = (tid >= off) ? s[tid - off] : 0;
        __syncthreads();
        s[tid] += add;
        __syncthreads();
    }
    if (tid < nb) bsums[tid] = s[tid] - v;  // exclusive
    if (tid == 511) bsums[nb] = s[511];     // total
}

__global__ void scan_add_kernel(int* __restrict__ row_start, const int* __restrict__ bsums,
                                int N, int nb) {
    int i = blockIdx.x * blockDim.x + threadIdx.x;
    if (i < N) row_start[i] += bsums[i >> 8];
    else if (i == N) row_start[N] = bsums[nb];
}

// ---------------- CSR fill: per-dst edge lists with precomputed norm ----------------
__global__ void fill_csr_kernel(const int* __restrict__ src, const int* __restrict__ dst,
                                const int* __restrict__ row_start, int* __restrict__ cursor,
                                const float* __restrict__ dis,
                                int* __restrict__ csr_src, float* __restrict__ csr_w, int E) {
    int e = blockIdx.x * blockDim.x + threadIdx.x;
    if (e < E) {
        int d = dst[e];
        int s = src[e];
        int pos = atomicAdd(&cursor[d], 1);
        int o = row_start[d] + pos;
        csr_src[o] = s;
        csr_w[o] = dis[s] * dis[d];
    }
}

// ---------------- dense linears, 8 nodes per 128-thread block ----------------
__global__ void linear_64_128_kernel(const float* __restrict__ x,
                                     const float* __restrict__ W,
                                     float* __restrict__ h, int N) {
    __shared__ float sx[8][64];
    int t = threadIdx.x;  // 0..127
    int nb = blockIdx.x * 8;
#pragma unroll
    for (int r = 0; r < 4; r++) {
        int idx = r * 128 + t;  // 0..511
        int n = idx >> 6, c = idx & 63;
        int gi = nb + n;
        sx[n][c] = (gi < N) ? x[gi * 64 + c] : 0.f;
    }
    __syncthreads();
    float acc[8] = {0, 0, 0, 0, 0, 0, 0, 0};
#pragma unroll 8
    for (int k = 0; k < 64; k++) {
        float w = W[k * 128 + t];
#pragma unroll
        for (int n = 0; n < 8; n++) acc[n] += sx[n][k] * w;
    }
#pragma unroll
    for (int n = 0; n < 8; n++) {
        int gi = nb + n;
        if (gi < N) h[gi * 128 + t] = acc[n];
    }
}

__global__ void linear_128_128_kernel(const float* __restrict__ x,
                                      const float* __restrict__ W,
                                      float* __restrict__ h, int N) {
    __shared__ float sx[8][128];
    int t = threadIdx.x;  // 0..127
    int nb = blockIdx.x * 8;
#pragma unroll
    for (int n = 0; n < 8; n++) {
        int gi = nb + n;
        sx[n][t] = (gi < N) ? x[gi * 128 + t] : 0.f;
    }
    __syncthreads();
    float acc[8] = {0, 0, 0, 0, 0, 0, 0, 0};
#pragma unroll 8
    for (int k = 0; k < 128; k++) {
        float w = W[k * 128 + t];
#pragma unroll
        for (int n = 0; n < 8; n++) acc[n] += sx[n][k] * w;
    }
#pragma unroll
    for (int n = 0; n < 8; n++) {
        int gi = nb + n;
        if (gi < N) h[gi * 128 + t] = acc[n];
    }
}

// ---------------- fused GCN aggregate: self-loop + bias + gather-sum (+ReLU) ----------------
// 256 threads = 2 nodes/block, 128 lanes per node
__global__ void gcn_aggregate_kernel(const float* __restrict__ h,
                                     const int* __restrict__ row_start,
                                     const int* __restrict__ csr_src,
                                     const float* __restrict__ csr_w,
                                     const float* __restrict__ dis,
                                     const float* __restrict__ b,
                                     float* __restrict__ out, int N) {
    int t = threadIdx.x;
    int node = blockIdx.x * 2 + (t >> 7);
    int j = t & 127;
    if (node >= N) return;
    int beg = row_start[node];
    int end = row_start[node + 1];
    float d = dis[node];
    float acc = h[node * 128 + j] * d * d + b[j];
    int k = beg;
    for (; k + 4 <= end; k += 4) {
        int s0 = csr_src[k], s1 = csr_src[k + 1], s2 = csr_src[k + 2], s3 = csr_src[k + 3];
        float w0 = csr_w[k], w1 = csr_w[k + 1], w2 = csr_w[k + 2], w3 = csr_w[k + 3];
        acc += h[s0 * 128 + j] * w0;
        acc += h[s1 * 128 + j] * w1;
        acc += h[s2 * 128 + j] * w2;
        acc += h[s3 * 128 + j] * w3;
    }
    for (; k < end; k++) acc += h[csr_src[k] * 128 + j] * csr_w[k];
    out[node * 128 + j] = fmaxf(acc, 0.f);  // both layers end in ReLU
}

// ---------------- global mean pool ----------------
__global__ void pool_kernel(const float* __restrict__ x,
                            const int* __restrict__ batch,
                            float* __restrict__ g,
                            float* __restrict__ cnt, int N) {
    int t = threadIdx.x;
    int i = blockIdx.x * 2 + (t >> 7);
    int j = t & 127;
    if (i < N) {
        int b = batch[i];
        atomicAdd(&g[b * 128 + j], x[i * 128 + j]);
        if (j == 0) atomicAdd(&cnt[b], 1.0f);
    }
}

// ---------------- head ----------------
__global__ void head_kernel(const float* __restrict__ g,
                            const float* __restrict__ cnt,
                            const float* __restrict__ Wfc,
                            const float* __restrict__ bfc,
                            const float* __restrict__ Wout,
                            const float* __restrict__ bout,
                            float* __restrict__ out) {
    int gr = blockIdx.x;
    int j = threadIdx.x;  // 0..127
    __shared__ float sg[128];
    __shared__ float sred[128];
    float c = fmaxf(cnt[gr], 1.0f);
    sg[j] = g[gr * 128 + j] / c;
    __syncthreads();
    float acc = bfc[j];
#pragma unroll
    for (int k = 0; k < 128; k++) acc += sg[k] * Wfc[k * 128 + j];
    float f = fmaxf(acc, 0.f);
    sred[j] = f * Wout[j];
    __syncthreads();
    if (j < 64) sred[j] += sred[j + 64];
    __syncthreads();
    if (j < 64) {
        float v = sred[j];
#pragma unroll
        for (int off = 32; off > 0; off >>= 1) v += __shfl_down(v, off);
        if (j == 0) {
            float logit = v + bout[0];
            out[gr] = 1.0f / (1.0f + expf(-logit));
            out[NUM_GRAPHS + gr] = logit;
        }
    }
}

extern "C" void kernel_launch(void* const* d_in, const int* in_sizes, int n_in,
                              void* d_out, int out_size, void* d_ws, size_t ws_size,
                              hipStream_t stream) {
    const int* tok   = (const int*)d_in[0];
    const int* eidx  = (const int*)d_in[1];
    const int* batch = (const int*)d_in[2];
    const float* emb = (const float*)d_in[3];
    const float* Wp  = (const float*)d_in[4];
    const float* bp  = (const float*)d_in[5];
    const float* W1  = (const float*)d_in[6];
    const float* b1  = (const float*)d_in[7];
    const float* W2  = (const float*)d_in[8];
    const float* b2  = (const float*)d_in[9];
    const float* Wfc = (const float*)d_in[10];
    const float* bfc = (const float*)d_in[11];
    const float* Wout= (const float*)d_in[12];
    const float* bout= (const float*)d_in[13];
    float* out = (float*)d_out;

    const int N = in_sizes[2];
    const int E = in_sizes[1] / 2;
    const int* src = eidx;
    const int* dst = eidx + E;
    const int nb_scan = (N + SCAN_B - 1) / SCAN_B;  // 391 for N=100k

    // workspace layout
    float* ws = (float*)d_ws;
    float* node = ws;                         // N*64 floats (reused for CSR after linear1)
    float* dis  = node + (size_t)N * 64;      // N
    float* hbuf = dis + N;                    // N*128
    float* xbuf = hbuf + (size_t)N * 128;     // N*128
    float* g    = xbuf + (size_t)N * 128;     // 1024*128
    float* cnt  = g + NUM_GRAPHS * 128;       // 1024
    int* row_start = (int*)(cnt + 1024);      // N+1
    int* hist      = row_start + (N + 1);     // N (doubles as cursor)
    int* bsums     = hist + N;                // up to 1024
    int* csr_src   = (int*)node;              // E ints  (overlaps node)
    float* csr_w   = (float*)(csr_src + E);   // E floats (overlaps node)

    // --- degree histogram + dis (needs hist zeroed) ---
    hipMemsetAsync(hist, 0, N * sizeof(int), stream);
    hist_kernel<<<(E + 255) / 256, 256, 0, stream>>>(dst, hist, E);
    dis_kernel<<<(N + 255) / 256, 256, 0, stream>>>(hist, dis, N);

    // --- exclusive scan hist -> row_start ---
    scan_local_kernel<<<nb_scan, SCAN_B, 0, stream>>>(hist, row_start, bsums, N);
    scan_bsums_kernel<<<1, 512, 0, stream>>>(bsums, nb_scan);
    scan_add_kernel<<<(N + 1 + 255) / 256, 256, 0, stream>>>(row_start, bsums, N, nb_scan);

    // --- node features + first linear (node buffer dead afterwards) ---
    embed_project_kernel<<<N, 64, 0, stream>>>(tok, emb, Wp, bp, node, N);
    linear_64_128_kernel<<<(N + 7) / 8, 128, 0, stream>>>(node, W1, hbuf, N);

    // --- CSR fill into (dead) node space; hist reused as cursor ---
    hipMemsetAsync(hist, 0, N * sizeof(int), stream);
    fill_csr_kernel<<<(E + 255) / 256, 256, 0, stream>>>(src, dst, row_start, hist, dis,
                                                         csr_src, csr_w, E);

    // --- GCN layer 1 aggregate (fused self+bias+relu) ---
    gcn_aggregate_kernel<<<(N + 1) / 2, 256, 0, stream>>>(hbuf, row_start, csr_src, csr_w,
                                                          dis, b1, xbuf, N);

    // --- GCN layer 2 ---
    linear_128_128_kernel<<<(N + 7) / 8, 128, 0, stream>>>(xbuf, W2, hbuf, N);
    gcn_aggregate_kernel<<<(N + 1) / 2, 256, 0, stream>>>(hbuf, row_start, csr_src, csr_w,
                                                          dis, b2, xbuf, N);

    // --- global mean pool ---
    hipMemsetAsync(g, 0, (NUM_GRAPHS * 128 + NUM_GRAPHS) * sizeof(float), stream);
    pool_kernel<<<(N + 1) / 2, 256, 0, stream>>>(xbuf, batch, g, cnt, N);

    // --- head ---
    head_kernel<<<NUM_GRAPHS, 128, 0, stream>>>(g, cnt, Wfc, bfc, Wout, bout, out);
}

// Round 3
// 761.301 us; speedup vs baseline: 2.7836x; 1.1418x over previous
//
#include <hip/hip_runtime.h>
#include <hip/hip_bf16.h>
#include <math.h>

#define N_TOKENS 16
#define TOK_DIM 64
#define NODE_DIM 64
#define HID 128
#define FC 128
#define NUM_GRAPHS 1024
#define SCAN_B 256

// ---------------- fused-weight precompute: Wf = Wp @ W1 (64x128), bf = bp @ W1 ----------------
__global__ void fuse_w_kernel(const float* __restrict__ Wp, const float* __restrict__ W1,
                              float* __restrict__ Wf) {
    int m = blockIdx.x;      // 0..63
    int j = threadIdx.x;     // 0..127
    float acc = 0.f;
#pragma unroll
    for (int d = 0; d < 64; d++) acc += Wp[m * 64 + d] * W1[d * 128 + j];
    Wf[m * 128 + j] = acc;
}

__global__ void fuse_b_kernel(const float* __restrict__ bp, const float* __restrict__ W1,
                              float* __restrict__ bf) {
    int j = threadIdx.x;     // 0..127
    float acc = 0.f;
#pragma unroll
    for (int d = 0; d < 64; d++) acc += bp[d] * W1[d * 128 + j];
    bf[j] = acc;
}

// ---------------- embed + token-mean + fused projection straight to h1[N,128] ----------------
// one block (128 threads) per node
__global__ void embed_project_kernel(const int* __restrict__ tok,
                                     const float* __restrict__ emb,
                                     const float* __restrict__ Wf,
                                     const float* __restrict__ bf,
                                     float* __restrict__ h,
                                     int N) {
    int i = blockIdx.x;
    if (i >= N) return;
    int j = threadIdx.x;  // 0..127
    __shared__ float mean[TOK_DIM];
    if (j < TOK_DIM) {
        float s = 0.f;
#pragma unroll
        for (int t = 0; t < N_TOKENS; t++) {
            int v = tok[i * N_TOKENS + t];
            s += emb[v * TOK_DIM + j];
        }
        mean[j] = s * (1.0f / (float)N_TOKENS);
    }
    __syncthreads();
    float acc = bf[j];
#pragma unroll
    for (int k = 0; k < TOK_DIM; k++) acc += mean[k] * Wf[k * 128 + j];
    h[i * 128 + j] = acc;
}

// ---------------- degree histogram (int) ----------------
__global__ void hist_kernel(const int* __restrict__ dst, int* __restrict__ hist, int E) {
    int e = blockIdx.x * blockDim.x + threadIdx.x;
    if (e < E) atomicAdd(&hist[dst[e]], 1);
}

__global__ void dis_kernel(const int* __restrict__ hist, float* __restrict__ dis, int N) {
    int i = blockIdx.x * blockDim.x + threadIdx.x;
    if (i < N) dis[i] = rsqrtf(1.0f + (float)hist[i]);  // +1 self loop
}

// ---------------- exclusive scan (3 kernels) ----------------
__global__ void scan_local_kernel(const int* __restrict__ hist, int* __restrict__ row_start,
                                  int* __restrict__ bsums, int N) {
    __shared__ int s[SCAN_B];
    int tid = threadIdx.x;
    int i = blockIdx.x * SCAN_B + tid;
    int v = (i < N) ? hist[i] : 0;
    s[tid] = v;
    __syncthreads();
    for (int off = 1; off < SCAN_B; off <<= 1) {
        int add = (tid >= off) ? s[tid - off] : 0;
        __syncthreads();
        s[tid] += add;
        __syncthreads();
    }
    if (i < N) row_start[i] = s[tid] - v;  // exclusive
    if (tid == SCAN_B - 1) bsums[blockIdx.x] = s[SCAN_B - 1];
}

// single block, 512 threads; nb <= 512
__global__ void scan_bsums_kernel(int* __restrict__ bsums, int nb) {
    __shared__ int s[512];
    int tid = threadIdx.x;
    int v = (tid < nb) ? bsums[tid] : 0;
    s[tid] = v;
    __syncthreads();
    for (int off = 1; off < 512; off <<= 1) {
        int add = (tid >= off) ? s[tid - off] : 0;
        __syncthreads();
        s[tid] += add;
        __syncthreads();
    }
    if (tid < nb) bsums[tid] = s[tid] - v;  // exclusive
    if (tid == 511) bsums[nb] = s[511];     // total
}

__global__ void scan_add_kernel(int* __restrict__ row_start, const int* __restrict__ bsums,
                                int N, int nb) {
    int i = blockIdx.x * blockDim.x + threadIdx.x;
    if (i < N) row_start[i] += bsums[i >> 8];
    else if (i == N) row_start[N] = bsums[nb];
}

// ---------------- CSR fill ----------------
__global__ void fill_csr_kernel(const int* __restrict__ src, const int* __restrict__ dst,
                                const int* __restrict__ row_start, int* __restrict__ cursor,
                                const float* __restrict__ dis,
                                int* __restrict__ csr_src, float* __restrict__ csr_w, int E) {
    int e = blockIdx.x * blockDim.x + threadIdx.x;
    if (e < E) {
        int d = dst[e];
        int s = src[e];
        int pos = atomicAdd(&cursor[d], 1);
        int o = row_start[d] + pos;
        csr_src[o] = s;
        csr_w[o] = dis[s] * dis[d];
    }
}

// ---------------- dense linear 128x128, 8 nodes per 128-thread block ----------------
__global__ void linear_128_128_kernel(const float* __restrict__ x,
                                      const float* __restrict__ W,
                                      float* __restrict__ h, int N) {
    __shared__ float sx[8][128];
    int t = threadIdx.x;  // 0..127
    int nb = blockIdx.x * 8;
#pragma unroll
    for (int n = 0; n < 8; n++) {
        int gi = nb + n;
        sx[n][t] = (gi < N) ? x[gi * 128 + t] : 0.f;
    }
    __syncthreads();
    float acc[8] = {0, 0, 0, 0, 0, 0, 0, 0};
#pragma unroll 8
    for (int k = 0; k < 128; k++) {
        float w = W[k * 128 + t];
#pragma unroll
        for (int n = 0; n < 8; n++) acc[n] += sx[n][k] * w;
    }
#pragma unroll
    for (int n = 0; n < 8; n++) {
        int gi = nb + n;
        if (gi < N) h[gi * 128 + t] = acc[n];
    }
}

// ---------------- fused GCN aggregate: self-loop + bias + gather-sum + ReLU ----------------
// 256 threads = 2 nodes/block, 128 lanes per node
__global__ void gcn_aggregate_kernel(const float* __restrict__ h,
                                     const int* __restrict__ row_start,
                                     const int* __restrict__ csr_src,
                                     const float* __restrict__ csr_w,
                                     const float* __restrict__ dis,
                                     const float* __restrict__ b,
                                     float* __restrict__ out, int N) {
    int t = threadIdx.x;
    int node = blockIdx.x * 2 + (t >> 7);
    int j = t & 127;
    if (node >= N) return;
    int beg = row_start[node];
    int end = row_start[node + 1];
    float d = dis[node];
    float acc = h[node * 128 + j] * d * d + b[j];
    int k = beg;
    for (; k + 4 <= end; k += 4) {
        int s0 = csr_src[k], s1 = csr_src[k + 1], s2 = csr_src[k + 2], s3 = csr_src[k + 3];
        float w0 = csr_w[k], w1 = csr_w[k + 1], w2 = csr_w[k + 2], w3 = csr_w[k + 3];
        acc += h[s0 * 128 + j] * w0;
        acc += h[s1 * 128 + j] * w1;
        acc += h[s2 * 128 + j] * w2;
        acc += h[s3 * 128 + j] * w3;
    }
    for (; k < end; k++) acc += h[csr_src[k] * 128 + j] * csr_w[k];
    out[node * 128 + j] = fmaxf(acc, 0.f);  // both layers end in ReLU
}

// ---------------- atomic-free global mean pool (batch is sorted) ----------------
__device__ __forceinline__ int lower_bound_i(const int* __restrict__ a, int n, int val) {
    int lo = 0, hi = n;
    while (lo < hi) {
        int mid = (lo + hi) >> 1;
        if (a[mid] < val) lo = mid + 1; else hi = mid;
    }
    return lo;
}

// one block (128 threads) per graph
__global__ void pool_mean_kernel(const float* __restrict__ x,
                                 const int* __restrict__ batch,
                                 float* __restrict__ g, int N) {
    int gr = blockIdx.x;
    int j = threadIdx.x;  // 0..127
    int beg = lower_bound_i(batch, N, gr);
    int end = lower_bound_i(batch, N, gr + 1);
    float acc = 0.f;
    int i = beg;
    for (; i + 4 <= end; i += 4) {
        acc += x[(size_t)i * 128 + j];
        acc += x[(size_t)(i + 1) * 128 + j];
        acc += x[(size_t)(i + 2) * 128 + j];
        acc += x[(size_t)(i + 3) * 128 + j];
    }
    for (; i < end; i++) acc += x[(size_t)i * 128 + j];
    float cnt = fmaxf((float)(end - beg), 1.0f);
    g[gr * 128 + j] = acc / cnt;
}

// ---------------- head (g already holds means) ----------------
__global__ void head_kernel(const float* __restrict__ g,
                            const float* __restrict__ Wfc,
                            const float* __restrict__ bfc,
                            const float* __restrict__ Wout,
                            const float* __restrict__ bout,
                            float* __restrict__ out) {
    int gr = blockIdx.x;
    int j = threadIdx.x;  // 0..127
    __shared__ float sg[128];
    __shared__ float sred[128];
    sg[j] = g[gr * 128 + j];
    __syncthreads();
    float acc = bfc[j];
#pragma unroll
    for (int k = 0; k < 128; k++) acc += sg[k] * Wfc[k * 128 + j];
    float f = fmaxf(acc, 0.f);
    sred[j] = f * Wout[j];
    __syncthreads();
    if (j < 64) sred[j] += sred[j + 64];
    __syncthreads();
    if (j < 64) {
        float v = sred[j];
#pragma unroll
        for (int off = 32; off > 0; off >>= 1) v += __shfl_down(v, off);
        if (j == 0) {
            float logit = v + bout[0];
            out[gr] = 1.0f / (1.0f + expf(-logit));
            out[NUM_GRAPHS + gr] = logit;
        }
    }
}

extern "C" void kernel_launch(void* const* d_in, const int* in_sizes, int n_in,
                              void* d_out, int out_size, void* d_ws, size_t ws_size,
                              hipStream_t stream) {
    const int* tok   = (const int*)d_in[0];
    const int* eidx  = (const int*)d_in[1];
    const int* batch = (const int*)d_in[2];
    const float* emb = (const float*)d_in[3];
    const float* Wp  = (const float*)d_in[4];
    const float* bp  = (const float*)d_in[5];
    const float* W1  = (const float*)d_in[6];
    const float* b1  = (const float*)d_in[7];
    const float* W2  = (const float*)d_in[8];
    const float* b2  = (const float*)d_in[9];
    const float* Wfc = (const float*)d_in[10];
    const float* bfc = (const float*)d_in[11];
    const float* Wout= (const float*)d_in[12];
    const float* bout= (const float*)d_in[13];
    float* out = (float*)d_out;

    const int N = in_sizes[2];
    const int E = in_sizes[1] / 2;
    const int* src = eidx;
    const int* dst = eidx + E;
    const int nb_scan = (N + SCAN_B - 1) / SCAN_B;

    // workspace layout
    float* ws = (float*)d_ws;
    float* dis  = ws;                          // N
    float* hbuf = dis + N;                     // N*128
    float* xbuf = hbuf + (size_t)N * 128;      // N*128
    float* g    = xbuf + (size_t)N * 128;      // 1024*128
    float* Wf   = g + NUM_GRAPHS * 128;        // 64*128
    float* bf   = Wf + 64 * 128;               // 128
    int* row_start = (int*)(bf + 128);         // N+1
    int* hist      = row_start + (N + 1);      // N (doubles as cursor)
    int* bsums     = hist + N;                 // up to 1024
    int* csr_src   = bsums + 1024;             // E
    float* csr_w   = (float*)(csr_src + E);    // E

    // --- fused projection weights ---
    fuse_w_kernel<<<64, 128, 0, stream>>>(Wp, W1, Wf);
    fuse_b_kernel<<<1, 128, 0, stream>>>(bp, W1, bf);

    // --- degree histogram + dis ---
    hipMemsetAsync(hist, 0, N * sizeof(int), stream);
    hist_kernel<<<(E + 255) / 256, 256, 0, stream>>>(dst, hist, E);
    dis_kernel<<<(N + 255) / 256, 256, 0, stream>>>(hist, dis, N);

    // --- exclusive scan hist -> row_start ---
    scan_local_kernel<<<nb_scan, SCAN_B, 0, stream>>>(hist, row_start, bsums, N);
    scan_bsums_kernel<<<1, 512, 0, stream>>>(bsums, nb_scan);
    scan_add_kernel<<<(N + 1 + 255) / 256, 256, 0, stream>>>(row_start, bsums, N, nb_scan);

    // --- CSR fill (hist reused as cursor) ---
    hipMemsetAsync(hist, 0, N * sizeof(int), stream);
    fill_csr_kernel<<<(E + 255) / 256, 256, 0, stream>>>(src, dst, row_start, hist, dis,
                                                         csr_src, csr_w, E);

    // --- embed + mean + fused (Wp@W1) projection -> h1 ---
    embed_project_kernel<<<N, 128, 0, stream>>>(tok, emb, Wf, bf, hbuf, N);

    // --- GCN layer 1 aggregate ---
    gcn_aggregate_kernel<<<(N + 1) / 2, 256, 0, stream>>>(hbuf, row_start, csr_src, csr_w,
                                                          dis, b1, xbuf, N);

    // --- GCN layer 2 ---
    linear_128_128_kernel<<<(N + 7) / 8, 128, 0, stream>>>(xbuf, W2, hbuf, N);
    gcn_aggregate_kernel<<<(N + 1) / 2, 256, 0, stream>>>(hbuf, row_start, csr_src, csr_w,
                                                          dis, b2, xbuf, N);

    // --- atomic-free global mean pool ---
    pool_mean_kernel<<<NUM_GRAPHS, 128, 0, stream>>>(xbuf, batch, g, N);

    // --- head ---
    head_kernel<<<NUM_GRAPHS, 128, 0, stream>>>(g, Wfc, bfc, Wout, bout, out);
}

// Round 4
// 677.523 us; speedup vs baseline: 3.1278x; 1.1237x over previous
//
#include <hip/hip_runtime.h>
#include <hip/hip_bf16.h>
#include <math.h>

#define N_TOKENS 16
#define TOK_DIM 64
#define NODE_DIM 64
#define HID 128
#define FC 128
#define NUM_GRAPHS 1024
#define SCAN_B 256

// ---------------- embed + token-mean + Wp projection -> node64[N,64] ----------------
// 256 threads = 4 nodes/block, one wave per node
__global__ void embed_project_kernel(const int* __restrict__ tok,
                                     const float* __restrict__ emb,
                                     const float* __restrict__ Wp,
                                     const float* __restrict__ bp,
                                     float* __restrict__ node64, int N) {
    __shared__ float smean[4][64];
    int t = threadIdx.x;
    int w = t >> 6, j = t & 63;
    int i = blockIdx.x * 4 + w;
    if (i < N) {
        int vt = tok[i * N_TOKENS + (j & 15)];  // lanes 0..15 hold the 16 token ids
        float s = 0.f;
#pragma unroll
        for (int tt = 0; tt < N_TOKENS; tt++) {
            int v = __shfl(vt, tt, 64);
            s += emb[v * TOK_DIM + j];
        }
        smean[w][j] = s * (1.0f / (float)N_TOKENS);
    }
    __syncthreads();
    if (i < N) {
        float acc = bp[j];
#pragma unroll
        for (int k = 0; k < TOK_DIM; k++) acc += smean[w][k] * Wp[k * NODE_DIM + j];
        node64[(size_t)i * 64 + j] = acc;
    }
}

// ---------------- degree histogram ----------------
__global__ void hist_kernel(const int* __restrict__ dst, int* __restrict__ hist, int E) {
    int e = blockIdx.x * blockDim.x + threadIdx.x;
    if (e < E) atomicAdd(&hist[dst[e]], 1);
}

// ---------------- scan local + dis + cursor reset (fused) ----------------
__global__ void scan_local_kernel(int* __restrict__ hist, int* __restrict__ row_start,
                                  int* __restrict__ bsums, float* __restrict__ dis, int N) {
    __shared__ int s[SCAN_B];
    int tid = threadIdx.x;
    int i = blockIdx.x * SCAN_B + tid;
    int v = (i < N) ? hist[i] : 0;
    s[tid] = v;
    __syncthreads();
    for (int off = 1; off < SCAN_B; off <<= 1) {
        int add = (tid >= off) ? s[tid - off] : 0;
        __syncthreads();
        s[tid] += add;
        __syncthreads();
    }
    if (i < N) {
        row_start[i] = s[tid] - v;                 // exclusive (block-local)
        dis[i] = rsqrtf(1.0f + (float)v);          // +1 self loop
        hist[i] = 0;                               // reset: hist doubles as cursor
    }
    if (tid == SCAN_B - 1) bsums[blockIdx.x] = s[SCAN_B - 1];
}

// single block, 512 threads; nb <= 512
__global__ void scan_bsums_kernel(int* __restrict__ bsums, int nb) {
    __shared__ int s[512];
    int tid = threadIdx.x;
    int v = (tid < nb) ? bsums[tid] : 0;
    s[tid] = v;
    __syncthreads();
    for (int off = 1; off < 512; off <<= 1) {
        int add = (tid >= off) ? s[tid - off] : 0;
        __syncthreads();
        s[tid] += add;
        __syncthreads();
    }
    if (tid < nb) bsums[tid] = s[tid] - v;  // exclusive
    if (tid == 511) bsums[nb] = s[511];     // total
}

__global__ void scan_add_kernel(int* __restrict__ row_start, const int* __restrict__ bsums,
                                int N, int nb) {
    int i = blockIdx.x * blockDim.x + threadIdx.x;
    if (i < N) row_start[i] += bsums[i >> 8];
    else if (i == N) row_start[N] = bsums[nb];
}

// ---------------- CSR fill, packed (src, weight) int2 ----------------
__global__ void fill_csr_kernel(const int* __restrict__ src, const int* __restrict__ dst,
                                const int* __restrict__ row_start, int* __restrict__ cursor,
                                const float* __restrict__ dis,
                                int2* __restrict__ csr, int E) {
    int e = blockIdx.x * blockDim.x + threadIdx.x;
    if (e < E) {
        int d = dst[e];
        int s = src[e];
        int pos = atomicAdd(&cursor[d], 1);
        int o = row_start[d] + pos;
        csr[o] = make_int2(s, __float_as_int(dis[s] * dis[d]));
    }
}

// ---------------- layer-1 fused: 64-dim aggregate + W1 transform + b1 + ReLU ----------------
// 256 threads = 4 nodes/block, one wave per node (lane j = feature 0..63)
__global__ void gcn_agg64_linear_kernel(const float* __restrict__ node64,
                                        const int* __restrict__ row_start,
                                        const int2* __restrict__ csr,
                                        const float* __restrict__ dis,
                                        const float* __restrict__ W1,
                                        const float* __restrict__ b1,
                                        float* __restrict__ x1, int N) {
    __shared__ float sagg[4][64];
    int t = threadIdx.x;
    int w = t >> 6, j = t & 63;
    int node = blockIdx.x * 4 + w;
    if (node < N) {
        int beg = row_start[node];
        int end = row_start[node + 1];
        float d = dis[node];
        float acc = node64[(size_t)node * 64 + j] * d * d;
        int k = beg;
        for (; k + 4 <= end; k += 4) {
            int2 e0 = csr[k], e1 = csr[k + 1], e2 = csr[k + 2], e3 = csr[k + 3];
            acc += node64[(size_t)e0.x * 64 + j] * __int_as_float(e0.y);
            acc += node64[(size_t)e1.x * 64 + j] * __int_as_float(e1.y);
            acc += node64[(size_t)e2.x * 64 + j] * __int_as_float(e2.y);
            acc += node64[(size_t)e3.x * 64 + j] * __int_as_float(e3.y);
        }
        for (; k < end; k++) {
            int2 e = csr[k];
            acc += node64[(size_t)e.x * 64 + j] * __int_as_float(e.y);
        }
        sagg[w][j] = acc;
    }
    __syncthreads();
    if (node < N) {
        float o0 = b1[j], o1 = b1[j + 64];
#pragma unroll
        for (int k = 0; k < 64; k++) {
            float a = sagg[w][k];
            o0 += a * W1[k * 128 + j];
            o1 += a * W1[k * 128 + j + 64];
        }
        x1[(size_t)node * 128 + j] = fmaxf(o0, 0.f);
        x1[(size_t)node * 128 + j + 64] = fmaxf(o1, 0.f);
    }
}

// ---------------- in-place dense linear 128x128, 8 nodes per 128-thread block ----------------
__global__ void linear_128_128_inplace_kernel(float* __restrict__ x,
                                              const float* __restrict__ W, int N) {
    __shared__ float sx[8][128];
    int t = threadIdx.x;  // 0..127
    int nb = blockIdx.x * 8;
#pragma unroll
    for (int n = 0; n < 8; n++) {
        int gi = nb + n;
        sx[n][t] = (gi < N) ? x[(size_t)gi * 128 + t] : 0.f;
    }
    __syncthreads();
    float acc[8] = {0, 0, 0, 0, 0, 0, 0, 0};
#pragma unroll 8
    for (int k = 0; k < 128; k++) {
        float w = W[k * 128 + t];
#pragma unroll
        for (int n = 0; n < 8; n++) acc[n] += sx[n][k] * w;
    }
#pragma unroll
    for (int n = 0; n < 8; n++) {
        int gi = nb + n;
        if (gi < N) x[(size_t)gi * 128 + t] = acc[n];
    }
}

// ---------------- layer-2 aggregate: 128-dim (float2), + b2 + ReLU ----------------
// 256 threads = 4 nodes/block, one wave per node, lane j = float2 pair (dims 2j,2j+1)
__global__ void gcn_agg128_kernel(const float* __restrict__ h,
                                  const int* __restrict__ row_start,
                                  const int2* __restrict__ csr,
                                  const float* __restrict__ dis,
                                  const float* __restrict__ b,
                                  float* __restrict__ out, int N) {
    int t = threadIdx.x;
    int w = t >> 6, j = t & 63;
    int node = blockIdx.x * 4 + w;
    if (node >= N) return;
    const float2* h2 = (const float2*)h;  // row stride 64 float2
    int beg = row_start[node];
    int end = row_start[node + 1];
    float d = dis[node];
    float2 self = h2[(size_t)node * 64 + j];
    float2 acc;
    acc.x = self.x * d * d + b[2 * j];
    acc.y = self.y * d * d + b[2 * j + 1];
    int k = beg;
    for (; k + 4 <= end; k += 4) {
        int2 e0 = csr[k], e1 = csr[k + 1], e2 = csr[k + 2], e3 = csr[k + 3];
        float2 v0 = h2[(size_t)e0.x * 64 + j];
        float2 v1 = h2[(size_t)e1.x * 64 + j];
        float2 v2 = h2[(size_t)e2.x * 64 + j];
        float2 v3 = h2[(size_t)e3.x * 64 + j];
        float w0 = __int_as_float(e0.y), w1 = __int_as_float(e1.y);
        float w2 = __int_as_float(e2.y), w3 = __int_as_float(e3.y);
        acc.x += v0.x * w0; acc.y += v0.y * w0;
        acc.x += v1.x * w1; acc.y += v1.y * w1;
        acc.x += v2.x * w2; acc.y += v2.y * w2;
        acc.x += v3.x * w3; acc.y += v3.y * w3;
    }
    for (; k < end; k++) {
        int2 e = csr[k];
        float2 v = h2[(size_t)e.x * 64 + j];
        float ww = __int_as_float(e.y);
        acc.x += v.x * ww; acc.y += v.y * ww;
    }
    float2 o;
    o.x = fmaxf(acc.x, 0.f);
    o.y = fmaxf(acc.y, 0.f);
    ((float2*)out)[(size_t)node * 64 + j] = o;
}

// ---------------- atomic-free global mean pool (batch sorted), float2 ----------------
__device__ __forceinline__ int lower_bound_i(const int* __restrict__ a, int n, int val) {
    int lo = 0, hi = n;
    while (lo < hi) {
        int mid = (lo + hi) >> 1;
        if (a[mid] < val) lo = mid + 1; else hi = mid;
    }
    return lo;
}

// 256 threads = 4 graphs/block, one wave per graph
__global__ void pool_mean_kernel(const float* __restrict__ x,
                                 const int* __restrict__ batch,
                                 float* __restrict__ g, int N) {
    int t = threadIdx.x;
    int w = t >> 6, j = t & 63;
    int gr = blockIdx.x * 4 + w;
    if (gr >= NUM_GRAPHS) return;
    int beg = lower_bound_i(batch, N, gr);
    int end = lower_bound_i(batch, N, gr + 1);
    const float2* x2 = (const float2*)x;
    float2 acc = make_float2(0.f, 0.f);
    int i = beg;
    for (; i + 4 <= end; i += 4) {
        float2 a0 = x2[(size_t)i * 64 + j];
        float2 a1 = x2[(size_t)(i + 1) * 64 + j];
        float2 a2 = x2[(size_t)(i + 2) * 64 + j];
        float2 a3 = x2[(size_t)(i + 3) * 64 + j];
        acc.x += a0.x + a1.x + a2.x + a3.x;
        acc.y += a0.y + a1.y + a2.y + a3.y;
    }
    for (; i < end; i++) {
        float2 a = x2[(size_t)i * 64 + j];
        acc.x += a.x; acc.y += a.y;
    }
    float inv = 1.0f / fmaxf((float)(end - beg), 1.0f);
    ((float2*)g)[(size_t)gr * 64 + j] = make_float2(acc.x * inv, acc.y * inv);
}

// ---------------- head ----------------
__global__ void head_kernel(const float* __restrict__ g,
                            const float* __restrict__ Wfc,
                            const float* __restrict__ bfc,
                            const float* __restrict__ Wout,
                            const float* __restrict__ bout,
                            float* __restrict__ out) {
    int gr = blockIdx.x;
    int j = threadIdx.x;  // 0..127
    __shared__ float sg[128];
    __shared__ float sred[128];
    sg[j] = g[gr * 128 + j];
    __syncthreads();
    float acc = bfc[j];
#pragma unroll
    for (int k = 0; k < 128; k++) acc += sg[k] * Wfc[k * 128 + j];
    float f = fmaxf(acc, 0.f);
    sred[j] = f * Wout[j];
    __syncthreads();
    if (j < 64) sred[j] += sred[j + 64];
    __syncthreads();
    if (j < 64) {
        float v = sred[j];
#pragma unroll
        for (int off = 32; off > 0; off >>= 1) v += __shfl_down(v, off);
        if (j == 0) {
            float logit = v + bout[0];
            out[gr] = 1.0f / (1.0f + expf(-logit));
            out[NUM_GRAPHS + gr] = logit;
        }
    }
}

extern "C" void kernel_launch(void* const* d_in, const int* in_sizes, int n_in,
                              void* d_out, int out_size, void* d_ws, size_t ws_size,
                              hipStream_t stream) {
    const int* tok   = (const int*)d_in[0];
    const int* eidx  = (const int*)d_in[1];
    const int* batch = (const int*)d_in[2];
    const float* emb = (const float*)d_in[3];
    const float* Wp  = (const float*)d_in[4];
    const float* bp  = (const float*)d_in[5];
    const float* W1  = (const float*)d_in[6];
    const float* b1  = (const float*)d_in[7];
    const float* W2  = (const float*)d_in[8];
    const float* b2  = (const float*)d_in[9];
    const float* Wfc = (const float*)d_in[10];
    const float* bfc = (const float*)d_in[11];
    const float* Wout= (const float*)d_in[12];
    const float* bout= (const float*)d_in[13];
    float* out = (float*)d_out;

    const int N = in_sizes[2];
    const int E = in_sizes[1] / 2;
    const int* src = eidx;
    const int* dst = eidx + E;
    const int nb_scan = (N + SCAN_B - 1) / SCAN_B;
    const int Np = (N + 3) & ~3;  // keep every segment even-sized for 8B alignment

    // workspace layout (4-byte units, all segments even => float2/int2 aligned)
    float* ws = (float*)d_ws;
    float* dis  = ws;                            // Np
    float* hbuf = dis + Np;                      // Np*128 (first Np*64 doubles as node64)
    float* node64 = hbuf;
    float* xbuf = hbuf + (size_t)Np * 128;       // Np*128
    float* g    = xbuf + (size_t)Np * 128;       // 1024*128
    int* row_start = (int*)(g + NUM_GRAPHS * 128); // Np+4
    int* hist      = row_start + Np + 4;         // Np (doubles as cursor)
    int* bsums     = hist + Np;                  // 1026
    int2* csr      = (int2*)(bsums + 1026);      // E int2

    // --- degree histogram ---
    hipMemsetAsync(hist, 0, N * sizeof(int), stream);
    hist_kernel<<<(E + 255) / 256, 256, 0, stream>>>(dst, hist, E);

    // --- scan (fused: dis + cursor reset) ---
    scan_local_kernel<<<nb_scan, SCAN_B, 0, stream>>>(hist, row_start, bsums, dis, N);
    scan_bsums_kernel<<<1, 512, 0, stream>>>(bsums, nb_scan);
    scan_add_kernel<<<(N + 1 + 255) / 256, 256, 0, stream>>>(row_start, bsums, N, nb_scan);

    // --- CSR fill (hist is the zeroed cursor) ---
    fill_csr_kernel<<<(E + 255) / 256, 256, 0, stream>>>(src, dst, row_start, hist, dis,
                                                         csr, E);

    // --- embed + mean + Wp -> node64 ---
    embed_project_kernel<<<(N + 3) / 4, 256, 0, stream>>>(tok, emb, Wp, bp, node64, N);

    // --- layer 1: aggregate at dim 64, then fused W1 + b1 + ReLU -> x1 ---
    gcn_agg64_linear_kernel<<<(N + 3) / 4, 256, 0, stream>>>(node64, row_start, csr, dis,
                                                             W1, b1, xbuf, N);

    // --- layer 2: in-place x1 @= W2, aggregate + b2 + ReLU -> hbuf ---
    linear_128_128_inplace_kernel<<<(N + 7) / 8, 128, 0, stream>>>(xbuf, W2, N);
    gcn_agg128_kernel<<<(N + 3) / 4, 256, 0, stream>>>(xbuf, row_start, csr, dis, b2,
                                                       hbuf, N);

    // --- global mean pool + head ---
    pool_mean_kernel<<<(NUM_GRAPHS + 3) / 4, 256, 0, stream>>>(hbuf, batch, g, N);
    head_kernel<<<NUM_GRAPHS, 128, 0, stream>>>(g, Wfc, bfc, Wout, bout, out);
}